// Round 8
// baseline (446.058 us; speedup 1.0000x reference)
//
#include <hip/hip_runtime.h>
#include <hip/hip_bf16.h>

#define NN 100000
#define NE 1280000
#define DD 64
#define RSHIFT 9             // 512-node dst ranges
#define NRANGE 196           // ceil(NN/512)
#define NPAD (NRANGE * 512)  // 100352
#define SECAP 640            // staged edge cap per 16-node tile (mean 205, 30+ sigma)

typedef __attribute__((ext_vector_type(8))) short bf16x8;
typedef __attribute__((ext_vector_type(4))) float f32x4;

static __device__ __forceinline__ unsigned short f2bf(float f) {
    __hip_bfloat16 h = __float2bfloat16(f);
    return *reinterpret_cast<unsigned short*>(&h);
}

// ---------------------------------------------------------------------------
// x (fp32) -> bf16 copy. Grid 6250 x 256, 4 elems/thread (exact: 6.4M).
// ---------------------------------------------------------------------------
__global__ __launch_bounds__(256) void f32_to_bf16_kernel(
    const float* __restrict__ in, unsigned short* __restrict__ out)
{
    int i = (blockIdx.x * 256 + threadIdx.x) * 4;
    float4 v = *(const float4*)(in + i);
    ushort4 o;
    o.x = f2bf(v.x); o.y = f2bf(v.y); o.z = f2bf(v.z); o.w = f2bf(v.w);
    *(ushort4*)(out + i) = o;
}

// ---------------------------------------------------------------------------
// B-fragment pre-pack: Bp[layer][t][256 threads][8] bf16. Grid 3.
// ---------------------------------------------------------------------------
__global__ __launch_bounds__(256) void bpack_kernel(
    const float* __restrict__ Wrel1, const float* __restrict__ Wroot1,
    const float* __restrict__ Wrel2, const float* __restrict__ Wroot2,
    const float* __restrict__ Wrel3, const float* __restrict__ Wroot3,
    unsigned short* __restrict__ Bp)
{
    int L = blockIdx.x;
    const float* Wrel  = (L == 0) ? Wrel1  : (L == 1) ? Wrel2  : Wrel3;
    const float* Wroot = (L == 0) ? Wroot1 : (L == 1) ? Wroot2 : Wroot3;
    int tid = threadIdx.x;
    int wv = tid >> 6, lane = tid & 63, quad = lane >> 4, m16 = lane & 15;
    int n = wv * 16 + m16;
    unsigned short* o = Bp + (size_t)L * 4 * 256 * 8;
#pragma unroll
    for (int t = 0; t < 4; ++t)
#pragma unroll
        for (int j = 0; j < 8; ++j) {
            int k = t * 32 + quad * 8 + j;
            float wval = (k < 64) ? Wrel[k * 64 + n] : Wroot[(k - 64) * 64 + n];
            o[((size_t)t * 256 + tid) * 8 + j] = f2bf(wval);
        }
}

// ---------------------------------------------------------------------------
// Range histogram: count edges per 512-node dst range. LDS-staged.
// ---------------------------------------------------------------------------
__global__ __launch_bounds__(256) void hist2_kernel(
    const int* __restrict__ dst, int* __restrict__ rangeCnt)
{
    __shared__ int h[256];
    int tid = threadIdx.x;
    h[tid] = 0;
    __syncthreads();
    int e0 = blockIdx.x * 1024 + tid * 4;
    int4 d4 = *(const int4*)(dst + e0);
    atomicAdd(&h[d4.x >> RSHIFT], 1);
    atomicAdd(&h[d4.y >> RSHIFT], 1);
    atomicAdd(&h[d4.z >> RSHIFT], 1);
    atomicAdd(&h[d4.w >> RSHIFT], 1);
    __syncthreads();
    if (tid < NRANGE && h[tid]) atomicAdd(&rangeCnt[tid], h[tid]);
}

// ---------------------------------------------------------------------------
// Exclusive scan of 196 range counts -> rangeBase[197] + gcur (P1 cursors).
// ---------------------------------------------------------------------------
__global__ __launch_bounds__(256) void scan196_kernel(
    const int* __restrict__ rangeCnt, int* __restrict__ rangeBase,
    int* __restrict__ gcur, int* __restrict__ rowptr)
{
    __shared__ int sd[256];
    int tid = threadIdx.x;
    int v = (tid < NRANGE) ? rangeCnt[tid] : 0;
    sd[tid] = v;
    __syncthreads();
    for (int o = 1; o < 256; o <<= 1) {
        int t = (tid >= o) ? sd[tid - o] : 0;
        __syncthreads();
        sd[tid] += t;
        __syncthreads();
    }
    if (tid < NRANGE) { int ex = sd[tid] - v; rangeBase[tid] = ex; gcur[tid] = ex; }
    if (tid == 0) { rangeBase[NRANGE] = NE; rowptr[NN] = NE; }
}

// ---------------------------------------------------------------------------
// P1: coarse bin by dst range. 512 thr, 2 edges/thr, wave-shfl scans ->
// only 5 barriers/block. Record: src(17b) | local-dst(9b @ bit17).
// ---------------------------------------------------------------------------
__global__ __launch_bounds__(512) void p1_bin_kernel(
    const int* __restrict__ src, const int* __restrict__ dst,
    const float* __restrict__ w, int* __restrict__ gcur,
    int2* __restrict__ ecoarse)
{
    __shared__ int2 stage[1024];
    __shared__ unsigned char sbkt[1024];
    __shared__ int cnt[256], ofs[256], gpos[256];
    __shared__ int wsum[4];

    int tid = threadIdx.x;
    int e0 = blockIdx.x * 1024 + tid * 2;
    int2   s2 = *(const int2*)(src + e0);
    int2   d2 = *(const int2*)(dst + e0);
    float2 w2 = *(const float2*)(w + e0);

    if (tid < 256) cnt[tid] = 0;
    __syncthreads();

    int ss[2] = {s2.x, s2.y};
    int dd[2] = {d2.x, d2.y};
    float ww[2] = {w2.x, w2.y};
    int b[2], p[2];
#pragma unroll
    for (int i = 0; i < 2; ++i) {
        b[i] = dd[i] >> RSHIFT;
        p[i] = atomicAdd(&cnt[b[i]], 1);
    }
    __syncthreads();

    // wave-level inclusive scan of 256 bins (4 waves x 64 lanes)
    if (tid < 256) {
        int v = cnt[tid];
        int lane6 = tid & 63;
        int sum = v;
#pragma unroll
        for (int o = 1; o < 64; o <<= 1) {
            int t = __shfl_up(sum, o);
            if (lane6 >= o) sum += t;
        }
        if (lane6 == 63) wsum[tid >> 6] = sum;
        ofs[tid] = sum - v;               // wave-local exclusive
    }
    __syncthreads();
    if (tid < 256) {
        int wid = tid >> 6;
        int pre = 0;
#pragma unroll
        for (int k = 0; k < 3; ++k) pre += (k < wid) ? wsum[k] : 0;
        ofs[tid] += pre;
        int cv = cnt[tid];
        if (tid < NRANGE && cv > 0) gpos[tid] = atomicAdd(&gcur[tid], cv);
    }
    __syncthreads();

#pragma unroll
    for (int i = 0; i < 2; ++i) {
        int slot = ofs[b[i]] + p[i];
        stage[slot] = make_int2(ss[i] | ((dd[i] & 511) << 17), __float_as_int(ww[i]));
        sbkt[slot] = (unsigned char)b[i];
    }
    __syncthreads();

#pragma unroll
    for (int u = 0; u < 2; ++u) {
        int j = tid + u * 512;
        int bb = sbkt[j];
        ecoarse[gpos[bb] + (j - ofs[bb])] = stage[j];
    }
}

// ---------------------------------------------------------------------------
// P2: per-range count + wave-shfl scan -> rowptr + cursors, then place.
// Grid NRANGE x 1024 thr. Int LDS atomics (native ds_add_rtn_u32).
// Final ebuf record: { src*32 (pre-scaled u32 row index), w }.
// ---------------------------------------------------------------------------
__global__ __launch_bounds__(1024) void p2_place_kernel(
    const int2* __restrict__ ecoarse, const int* __restrict__ rangeBase,
    int* __restrict__ rowptr, int2* __restrict__ ebuf)
{
    __shared__ int cnt[512];
    __shared__ int wsum[8];
    int r = blockIdx.x, tid = threadIdx.x;
    int beg = rangeBase[r], end = rangeBase[r + 1];

    if (tid < 512) cnt[tid] = 0;
    __syncthreads();

    for (int j = beg + tid; j < end; j += 1024) {
        int2 rec = ecoarse[j];
        atomicAdd(&cnt[(rec.x >> 17) & 511], 1);
    }
    __syncthreads();

    // scan 512 counters: 8 waves x 64 lanes, shfl inclusive + cross-wave fix
    int v = 0, sum = 0;
    if (tid < 512) {
        v = cnt[tid]; sum = v;
        int lane6 = tid & 63;
#pragma unroll
        for (int o = 1; o < 64; o <<= 1) {
            int t = __shfl_up(sum, o);
            if (lane6 >= o) sum += t;
        }
        if (lane6 == 63) wsum[tid >> 6] = sum;
    }
    __syncthreads();
    if (tid < 512) {
        int wid = tid >> 6;
        int pre = 0;
#pragma unroll
        for (int k = 0; k < 7; ++k) pre += (k < wid) ? wsum[k] : 0;
        int ex = beg + pre + sum - v;       // exclusive cursor for node tid
        rowptr[(r << RSHIFT) + tid] = ex;
        cnt[tid] = ex;
    }
    __syncthreads();

    for (int j = beg + tid; j < end; j += 1024) {
        int2 rec = ecoarse[j];
        int dl = (rec.x >> 17) & 511;
        int pp = atomicAdd(&cnt[dl], 1);
        ebuf[pp] = make_int2((rec.x & 0x1FFFF) << 5, rec.y);   // pre-scaled src*32
    }
}

// ---------------------------------------------------------------------------
// FUSED layer: CSR gather + dual GEMM + bias (+ReLU). Block = 512 thr =
// 8 waves = 16 nodes, half-wave per node (32 lanes = 32 channel pairs).
// The block's WHOLE edge list (<=SECAP recs) is staged to LDS once (one
// coalesced pass), then each half-wave streams its records via ds_read_b64
// at uniform addr + immediate offsets: no shfl, no bpermute, no addr VALU.
// Record src is pre-scaled (*32) -> row index is one v_add. 16 slots
// unrolled -> 16 row loads in flight/wave. Tail + (improbable) overflow
// handled by uniform global broadcast loads. Staging + MFMA + epilogue
// identical to the verified r6 kernel.
// ---------------------------------------------------------------------------
template <bool RELU, bool OUT32>
__global__ __launch_bounds__(512) void fused_layer_kernel(
    const unsigned short* __restrict__ hb,   // input node table (gather + root)
    const int* __restrict__ rowptr,
    const int2* __restrict__ ebuf,
    const unsigned short* __restrict__ Bp,   // [4][256][8] bf16 (this layer)
    const float* __restrict__ brel,
    void* __restrict__ outp)
{
    __shared__ __align__(16) unsigned int AstW[4 * 256];   // 4 KB
    __shared__ __align__(16) int2 se[SECAP];               // 5 KB edge stage

    int tid = threadIdx.x;
    int lane = tid & 63;
    int wv = tid >> 6;            // 0..7
    int half = lane >> 5;         // node parity within wave
    int ch = lane & 31;           // channel pair
    int base = blockIdx.x * 16;
    int node = base + wv * 2 + half;

    const unsigned int* __restrict__ hw = (const unsigned int*)hb;

    // block edge window (uniform) + stage whole tile edge list to LDS
    int ebeg = __builtin_amdgcn_readfirstlane(rowptr[base]);
    int eend = __builtin_amdgcn_readfirstlane(rowptr[base + 16]);
    int ecnt = eend - ebeg;
    int scnt = ecnt < SECAP ? ecnt : SECAP;
    for (int j = tid; j < scnt; j += 512) se[j] = ebuf[ebeg + j];

    // B fragments + bias preloaded (only used by waves 0-3)
    bf16x8 bfrag[4];
    float bias = 0.f;
    if (wv < 4) {
#pragma unroll
        for (int t2 = 0; t2 < 4; ++t2)
            bfrag[t2] = *(const bf16x8*)(Bp + ((size_t)t2 * 256 + tid) * 8);
        bias = brel[(wv << 4) | (lane & 15)];
    }

    // root row (own node) issued early
    unsigned rootp = hw[(size_t)node * 32 + ch];

    int beg = rowptr[node];
    int end = rowptr[node + 1];
    int deg = end - beg;
    int labeg = beg - ebeg;       // local index of this node's first edge

    __syncthreads();              // se visible

    float aL[4] = {0.f, 0.f, 0.f, 0.f};
    float aH[4] = {0.f, 0.f, 0.f, 0.f};

    // ---- main: full 16-slot chunks from LDS (uniform ds_read_b64 + imm) ----
    int c = 0;
    for (; c + 16 <= deg && labeg + c + 16 <= scnt; c += 16) {
        int lb = labeg + c;
        int2 rec[16];
#pragma unroll
        for (int i = 0; i < 16; ++i) rec[i] = se[lb + i];
#pragma unroll
        for (int i = 0; i < 16; ++i) {
            float w = __int_as_float(rec[i].y);
            unsigned v = hw[rec[i].x + ch];          // pre-scaled src*32
            aL[i & 3] = fmaf(w, __uint_as_float(v << 16), aL[i & 3]);
            aH[i & 3] = fmaf(w, __uint_as_float(v & 0xFFFF0000u), aH[i & 3]);
        }
    }

    // ---- tail / overflow: uniform global broadcast loads, masked ----
    for (; c < deg; c += 16) {
#pragma unroll
        for (int i = 0; i < 16; ++i) {
            int j = c + i;
            bool ok = j < deg;
            int2 rec = ebuf[beg + (ok ? j : c)];
            float w = ok ? __int_as_float(rec.y) : 0.f;
            unsigned v = hw[rec.x + ch];
            aL[i & 3] = fmaf(w, __uint_as_float(v << 16), aL[i & 3]);
            aH[i & 3] = fmaf(w, __uint_as_float(v & 0xFFFF0000u), aH[i & 3]);
        }
    }
    float accL = (aL[0] + aL[1]) + (aL[2] + aL[3]);
    float accH = (aH[0] + aH[1]) + (aH[2] + aH[3]);

    // stage agg (k 0..63) and root (k 64..127) pairs in fragment order
    int m = wv * 2 + half;                     // row 0..15
    int t = ch >> 4, q = (ch >> 2) & 3, jj = ch & 3;
    unsigned pack = ((unsigned)f2bf(accH) << 16) | (unsigned)f2bf(accL);
    AstW[t * 256 + (q * 16 + m) * 4 + jj] = pack;
    AstW[(2 + t) * 256 + (q * 16 + m) * 4 + jj] = rootp;
    __syncthreads();

    if (wv < 4) {
        int quad = lane >> 4, m16 = lane & 15;
        int n = wv * 16 + m16;
        f32x4 cacc = {0.f, 0.f, 0.f, 0.f};
#pragma unroll
        for (int t2 = 0; t2 < 4; ++t2) {
            bf16x8 a = *(const bf16x8*)&AstW[t2 * 256 + lane * 4];
            cacc = __builtin_amdgcn_mfma_f32_16x16x32_bf16(a, bfrag[t2], cacc, 0, 0, 0);
        }
#pragma unroll
        for (int reg = 0; reg < 4; ++reg) {
            int row = quad * 4 + reg;
            size_t onode = (size_t)base + row;
            float v2 = cacc[reg] + bias;
            if (RELU) v2 = fmaxf(v2, 0.f);
            if (OUT32) ((float*)outp)[onode * DD + n] = v2;
            else       ((unsigned short*)outp)[onode * DD + n] = f2bf(v2);
        }
    }
}

extern "C" void kernel_launch(void* const* d_in, const int* in_sizes, int n_in,
                              void* d_out, int out_size, void* d_ws, size_t ws_size,
                              hipStream_t stream)
{
    const float* x     = (const float*)d_in[0];
    const int*   ei    = (const int*)d_in[1];
    const float* w     = (const float*)d_in[2];
    const float* Wrel1 = (const float*)d_in[4];
    const float* brel1 = (const float*)d_in[5];
    const float* Wroot1= (const float*)d_in[6];
    const float* Wrel2 = (const float*)d_in[7];
    const float* brel2 = (const float*)d_in[8];
    const float* Wroot2= (const float*)d_in[9];
    const float* Wrel3 = (const float*)d_in[10];
    const float* brel3 = (const float*)d_in[11];
    const float* Wroot3= (const float*)d_in[12];

    float* out = (float*)d_out;

    // workspace: ebuf | ecoarse->xb alias | hb1 | hb2 | ints | Bp
    char* ws = (char*)d_ws;
    int2*  ebuf    = (int2*)ws;                ws += (size_t)NE * 8;            // 10.24 MB
    int2*  ecoarse = (int2*)ws;                                                // aliases xb
    unsigned short* xb  = (unsigned short*)ws; ws += (size_t)NN * DD * 2;       // 12.8 MB (>= ecoarse 10.24)
    unsigned short* hb1 = (unsigned short*)ws; ws += (size_t)NN * DD * 2;       // 12.8 MB
    unsigned short* hb2 = (unsigned short*)ws; ws += (size_t)NN * DD * 2;       // 12.8 MB
    int*   rowptr = (int*)ws;                  ws += (size_t)(NPAD + 16) * 4;
    int*   rangeCnt  = (int*)ws;               ws += (size_t)256 * 4;
    int*   rangeBase = (int*)ws;               ws += (size_t)256 * 4;
    int*   gcur      = (int*)ws;               ws += (size_t)256 * 4;
    unsigned short* Bp = (unsigned short*)ws;  // 3 * 16 KB

    const int* src = ei;
    const int* dst = ei + NE;

    // ---- CSR build: range hist -> scan -> bin -> place ----
    hipMemsetAsync(rangeCnt, 0, NRANGE * 4, stream);
    bpack_kernel<<<3, 256, 0, stream>>>(Wrel1, Wroot1, Wrel2, Wroot2, Wrel3, Wroot3, Bp);
    hist2_kernel<<<1250, 256, 0, stream>>>(dst, rangeCnt);
    scan196_kernel<<<1, 256, 0, stream>>>(rangeCnt, rangeBase, gcur, rowptr);
    p1_bin_kernel<<<1250, 512, 0, stream>>>(src, dst, w, gcur, ecoarse);
    p2_place_kernel<<<NRANGE, 1024, 0, stream>>>(ecoarse, rangeBase, rowptr, ebuf);

    // ---- xb = bf16(x) (ecoarse dead now) ----
    f32_to_bf16_kernel<<<6250, 256, 0, stream>>>(x, xb);

    // ---- 3 fused layers (ping-pong xb -> hb1 -> hb2 -> out) ----
    fused_layer_kernel<true, false><<<NN / 16, 512, 0, stream>>>(
        xb, rowptr, ebuf, Bp, brel1, hb1);
    fused_layer_kernel<true, false><<<NN / 16, 512, 0, stream>>>(
        hb1, rowptr, ebuf, Bp + (size_t)4 * 256 * 8, brel2, hb2);
    fused_layer_kernel<false, true><<<NN / 16, 512, 0, stream>>>(
        hb2, rowptr, ebuf, Bp + (size_t)8 * 256 * 8, brel3, out);
}

// Round 9
// 289.224 us; speedup vs baseline: 1.5423x; 1.5423x over previous
//
#include <hip/hip_runtime.h>
#include <hip/hip_bf16.h>

#define NN 100000
#define NE 1280000
#define DD 64
#define RSHIFT 8             // 256-node dst ranges
#define NRANGE 392           // ceil(NN/256) = 391, pad to 392
#define NPAD (NRANGE * 256)  // 100352

typedef __attribute__((ext_vector_type(8))) short bf16x8;
typedef __attribute__((ext_vector_type(4))) float f32x4;

static __device__ __forceinline__ unsigned short f2bf(float f) {
    __hip_bfloat16 h = __float2bfloat16(f);
    return *reinterpret_cast<unsigned short*>(&h);
}

// ---------------------------------------------------------------------------
// x (fp32) -> bf16 copy. Grid 6250 x 256, 4 elems/thread (exact: 6.4M).
// ---------------------------------------------------------------------------
__global__ __launch_bounds__(256) void f32_to_bf16_kernel(
    const float* __restrict__ in, unsigned short* __restrict__ out)
{
    int i = (blockIdx.x * 256 + threadIdx.x) * 4;
    float4 v = *(const float4*)(in + i);
    ushort4 o;
    o.x = f2bf(v.x); o.y = f2bf(v.y); o.z = f2bf(v.z); o.w = f2bf(v.w);
    *(ushort4*)(out + i) = o;
}

// ---------------------------------------------------------------------------
// B-fragment pre-pack: Bp[layer][t][256 threads][8] bf16. Grid 3.
// ---------------------------------------------------------------------------
__global__ __launch_bounds__(256) void bpack_kernel(
    const float* __restrict__ Wrel1, const float* __restrict__ Wroot1,
    const float* __restrict__ Wrel2, const float* __restrict__ Wroot2,
    const float* __restrict__ Wrel3, const float* __restrict__ Wroot3,
    unsigned short* __restrict__ Bp)
{
    int L = blockIdx.x;
    const float* Wrel  = (L == 0) ? Wrel1  : (L == 1) ? Wrel2  : Wrel3;
    const float* Wroot = (L == 0) ? Wroot1 : (L == 1) ? Wroot2 : Wroot3;
    int tid = threadIdx.x;
    int wv = tid >> 6, lane = tid & 63, quad = lane >> 4, m16 = lane & 15;
    int n = wv * 16 + m16;
    unsigned short* o = Bp + (size_t)L * 4 * 256 * 8;
#pragma unroll
    for (int t = 0; t < 4; ++t)
#pragma unroll
        for (int j = 0; j < 8; ++j) {
            int k = t * 32 + quad * 8 + j;
            float wval = (k < 64) ? Wrel[k * 64 + n] : Wroot[(k - 64) * 64 + n];
            o[((size_t)t * 256 + tid) * 8 + j] = f2bf(wval);
        }
}

// ---------------------------------------------------------------------------
// Range histogram: edges per 256-node dst range (392 bins). LDS-staged.
// ---------------------------------------------------------------------------
__global__ __launch_bounds__(256) void hist392_kernel(
    const int* __restrict__ dst, int* __restrict__ rangeCnt)
{
    __shared__ int h[NRANGE];
    int tid = threadIdx.x;
    if (tid < NRANGE) h[tid] = 0;
    if (tid + 256 < NRANGE) h[tid + 256] = 0;
    __syncthreads();
    int e0 = blockIdx.x * 1024 + tid * 4;
    int4 d4 = *(const int4*)(dst + e0);
    atomicAdd(&h[d4.x >> RSHIFT], 1);
    atomicAdd(&h[d4.y >> RSHIFT], 1);
    atomicAdd(&h[d4.z >> RSHIFT], 1);
    atomicAdd(&h[d4.w >> RSHIFT], 1);
    __syncthreads();
    if (tid < NRANGE && h[tid]) atomicAdd(&rangeCnt[tid], h[tid]);
    if (tid + 256 < NRANGE && h[tid + 256]) atomicAdd(&rangeCnt[tid + 256], h[tid + 256]);
}

// ---------------------------------------------------------------------------
// Exclusive scan of 392 range counts -> rangeBase[393] + gcur (P1 cursors).
// ---------------------------------------------------------------------------
__global__ __launch_bounds__(512) void scan392_kernel(
    const int* __restrict__ rangeCnt, int* __restrict__ rangeBase,
    int* __restrict__ gcur, int* __restrict__ rowptr)
{
    __shared__ int sd[512];
    int tid = threadIdx.x;
    int v = (tid < NRANGE) ? rangeCnt[tid] : 0;
    sd[tid] = v;
    __syncthreads();
    for (int o = 1; o < 512; o <<= 1) {
        int t = (tid >= o) ? sd[tid - o] : 0;
        __syncthreads();
        sd[tid] += t;
        __syncthreads();
    }
    if (tid < NRANGE) { int ex = sd[tid] - v; rangeBase[tid] = ex; gcur[tid] = ex; }
    if (tid == 0) { rangeBase[NRANGE] = NE; rowptr[NN] = NE; }
}

// ---------------------------------------------------------------------------
// P1: bin edges by 256-node dst range. 512 thr, 2 edges/thr, wave-shfl scan
// over 392 bins (7 waves, last partial). Record: src(17b)|local-dst(8b@17).
// ---------------------------------------------------------------------------
__global__ __launch_bounds__(512) void p1_bin_kernel(
    const int* __restrict__ src, const int* __restrict__ dst,
    const float* __restrict__ w, int* __restrict__ gcur,
    int2* __restrict__ ecoarse)
{
    __shared__ int2 stage[1024];
    __shared__ unsigned short sbkt[1024];
    __shared__ int cnt[NRANGE], ofs[NRANGE], gpos[NRANGE];
    __shared__ int wsum[8];

    int tid = threadIdx.x;
    int e0 = blockIdx.x * 1024 + tid * 2;
    int2   s2 = *(const int2*)(src + e0);
    int2   d2 = *(const int2*)(dst + e0);
    float2 w2 = *(const float2*)(w + e0);

    if (tid < NRANGE) cnt[tid] = 0;
    __syncthreads();

    int ss[2] = {s2.x, s2.y};
    int dd[2] = {d2.x, d2.y};
    float ww[2] = {w2.x, w2.y};
    int b[2], p[2];
#pragma unroll
    for (int i = 0; i < 2; ++i) {
        b[i] = dd[i] >> RSHIFT;
        p[i] = atomicAdd(&cnt[b[i]], 1);
    }
    __syncthreads();

    int sum = 0, v = 0;
    if (tid < NRANGE) {
        v = cnt[tid];
        int lane6 = tid & 63;
        sum = v;
#pragma unroll
        for (int o = 1; o < 64; o <<= 1) {
            int t = __shfl_up(sum, o);
            if (lane6 >= o) sum += t;
        }
        if (lane6 == 63 || tid == NRANGE - 1) wsum[tid >> 6] = sum;
        ofs[tid] = sum - v;
    }
    __syncthreads();
    if (tid < NRANGE) {
        int wid = tid >> 6;
        int pre = 0;
#pragma unroll
        for (int k = 0; k < 6; ++k) pre += (k < wid) ? wsum[k] : 0;
        ofs[tid] += pre;
        if (v > 0) gpos[tid] = atomicAdd(&gcur[tid], v);
    }
    __syncthreads();

#pragma unroll
    for (int i = 0; i < 2; ++i) {
        int slot = ofs[b[i]] + p[i];
        stage[slot] = make_int2(ss[i] | ((dd[i] & 255) << 17), __float_as_int(ww[i]));
        sbkt[slot] = (unsigned short)b[i];
    }
    __syncthreads();

#pragma unroll
    for (int u = 0; u < 2; ++u) {
        int j = tid + u * 512;
        int bb = sbkt[j];
        ecoarse[gpos[bb] + (j - ofs[bb])] = stage[j];
    }
}

// ---------------------------------------------------------------------------
// P2: per-range count + wave-shfl scan -> rowptr + cursors, then place.
// Grid NRANGE(392) x 512 thr. Int LDS atomics (native).
// Final ebuf record: { src*128 (pre-scaled BYTE row offset), w }.
// ---------------------------------------------------------------------------
__global__ __launch_bounds__(512) void p2_place_kernel(
    const int2* __restrict__ ecoarse, const int* __restrict__ rangeBase,
    int* __restrict__ rowptr, int2* __restrict__ ebuf)
{
    __shared__ int cnt[256];
    __shared__ int wsum[4];
    int r = blockIdx.x, tid = threadIdx.x;
    int beg = rangeBase[r], end = rangeBase[r + 1];

    if (tid < 256) cnt[tid] = 0;
    __syncthreads();

    for (int j = beg + tid; j < end; j += 512) {
        int2 rec = ecoarse[j];
        atomicAdd(&cnt[(rec.x >> 17) & 255], 1);
    }
    __syncthreads();

    int v = 0, sum = 0;
    if (tid < 256) {
        v = cnt[tid]; sum = v;
        int lane6 = tid & 63;
#pragma unroll
        for (int o = 1; o < 64; o <<= 1) {
            int t = __shfl_up(sum, o);
            if (lane6 >= o) sum += t;
        }
        if (lane6 == 63) wsum[tid >> 6] = sum;
    }
    __syncthreads();
    if (tid < 256) {
        int wid = tid >> 6;
        int pre = 0;
#pragma unroll
        for (int k = 0; k < 3; ++k) pre += (k < wid) ? wsum[k] : 0;
        int ex = beg + pre + sum - v;       // exclusive cursor for node tid
        rowptr[(r << RSHIFT) + tid] = ex;
        cnt[tid] = ex;
    }
    __syncthreads();

    for (int j = beg + tid; j < end; j += 512) {
        int2 rec = ecoarse[j];
        int dl = (rec.x >> 17) & 255;
        int pp = atomicAdd(&cnt[dl], 1);
        ebuf[pp] = make_int2((rec.x & 0x1FFFF) << 7, rec.y);   // src*128 bytes
    }
}

// ---------------------------------------------------------------------------
// FUSED layer: CSR gather + dual GEMM + bias (+ReLU). Block = 512 thr =
// 8 waves = 16 nodes, half-wave per node (32 lanes = 32 channel pairs).
// Per 32-edge chunk: 64 lanes cooperatively load the chunk's records and
// ds_write_b64 them to a per-wave LDS slab (pad slots get w=0 AT STAGE
// TIME -> zero per-slot masking); each half-wave then streams 16 slots via
// half-uniform ds_read_b64 (broadcast, conflict-free) -- no bpermute, no
// cndmasks. Row address = pre-scaled byte offset + (ch*4): one v_add +
// saddr load. 16 row loads in flight/wave. Same-wave LDS RAW needs no
// barrier. Staging + MFMA + epilogue identical to verified r6.
// ---------------------------------------------------------------------------
template <bool RELU, bool OUT32>
__global__ __launch_bounds__(512) void fused_layer_kernel(
    const unsigned short* __restrict__ hb,   // input node table (gather + root)
    const int* __restrict__ rowptr,
    const int2* __restrict__ ebuf,
    const unsigned short* __restrict__ Bp,   // [4][256][8] bf16 (this layer)
    const float* __restrict__ brel,
    void* __restrict__ outp)
{
    __shared__ __align__(16) unsigned int AstW[4 * 256];   // 4 KB
    __shared__ __align__(16) int2 seW[8][64];              // 4 KB per-wave slabs

    int tid = threadIdx.x;
    int lane = tid & 63;
    int wv = tid >> 6;            // 0..7
    int half = lane >> 5;         // node parity within wave
    int ch = lane & 31;           // channel pair
    int base = blockIdx.x * 16;
    int node = base + wv * 2 + half;

    const char* __restrict__ hbase = (const char*)hb;
    unsigned chB = (unsigned)ch * 4;

    // B fragments + bias preloaded (only used by waves 0-3)
    bf16x8 bfrag[4];
    float bias = 0.f;
    if (wv < 4) {
#pragma unroll
        for (int t2 = 0; t2 < 4; ++t2)
            bfrag[t2] = *(const bf16x8*)(Bp + ((size_t)t2 * 256 + tid) * 8);
        bias = brel[(wv << 4) | (lane & 15)];
    }

    // root row (own node) issued early
    unsigned rootp = *(const unsigned*)(hbase + (size_t)node * 128 + chB);

    int beg = rowptr[node];
    int end = rowptr[node + 1];
    int deg = end - beg;

    float aL[4] = {0.f, 0.f, 0.f, 0.f};
    float aH[4] = {0.f, 0.f, 0.f, 0.f};

    for (int c = 0; c < deg; c += 32) {
        int nsl = deg - c; if (nsl > 32) nsl = 32;
        // stage chunk records; pad slots get w=0 (one select per chunk)
        {
            int j = c + ch;
            bool ok = j < deg;
            int2 e = ebuf[beg + (ok ? j : (deg - 1))];
            if (!ok) e.y = 0;
            seW[wv][half * 32 + ch] = e;
        }
        for (int s0 = 0; s0 < nsl; s0 += 16) {
#pragma unroll
            for (int i = 0; i < 16; ++i) {
                int2 rec = seW[wv][half * 32 + s0 + i];   // broadcast ds_read_b64
                float w = __int_as_float(rec.y);
                unsigned v = *(const unsigned*)(hbase + ((unsigned)rec.x + chB));
                aL[i & 3] = fmaf(w, __uint_as_float(v << 16), aL[i & 3]);
                aH[i & 3] = fmaf(w, __uint_as_float(v & 0xFFFF0000u), aH[i & 3]);
            }
        }
    }
    float accL = (aL[0] + aL[1]) + (aL[2] + aL[3]);
    float accH = (aH[0] + aH[1]) + (aH[2] + aH[3]);

    // stage agg (k 0..63) and root (k 64..127) pairs in fragment order
    int m = wv * 2 + half;                     // row 0..15
    int t = ch >> 4, q = (ch >> 2) & 3, jj = ch & 3;
    unsigned pack = ((unsigned)f2bf(accH) << 16) | (unsigned)f2bf(accL);
    AstW[t * 256 + (q * 16 + m) * 4 + jj] = pack;
    AstW[(2 + t) * 256 + (q * 16 + m) * 4 + jj] = rootp;
    __syncthreads();

    if (wv < 4) {
        int quad = lane >> 4, m16 = lane & 15;
        int n = wv * 16 + m16;
        f32x4 cacc = {0.f, 0.f, 0.f, 0.f};
#pragma unroll
        for (int t2 = 0; t2 < 4; ++t2) {
            bf16x8 a = *(const bf16x8*)&AstW[t2 * 256 + lane * 4];
            cacc = __builtin_amdgcn_mfma_f32_16x16x32_bf16(a, bfrag[t2], cacc, 0, 0, 0);
        }
#pragma unroll
        for (int reg = 0; reg < 4; ++reg) {
            int row = quad * 4 + reg;
            size_t onode = (size_t)base + row;
            float v2 = cacc[reg] + bias;
            if (RELU) v2 = fmaxf(v2, 0.f);
            if (OUT32) ((float*)outp)[onode * DD + n] = v2;
            else       ((unsigned short*)outp)[onode * DD + n] = f2bf(v2);
        }
    }
}

extern "C" void kernel_launch(void* const* d_in, const int* in_sizes, int n_in,
                              void* d_out, int out_size, void* d_ws, size_t ws_size,
                              hipStream_t stream)
{
    const float* x     = (const float*)d_in[0];
    const int*   ei    = (const int*)d_in[1];
    const float* w     = (const float*)d_in[2];
    const float* Wrel1 = (const float*)d_in[4];
    const float* brel1 = (const float*)d_in[5];
    const float* Wroot1= (const float*)d_in[6];
    const float* Wrel2 = (const float*)d_in[7];
    const float* brel2 = (const float*)d_in[8];
    const float* Wroot2= (const float*)d_in[9];
    const float* Wrel3 = (const float*)d_in[10];
    const float* brel3 = (const float*)d_in[11];
    const float* Wroot3= (const float*)d_in[12];

    float* out = (float*)d_out;

    // workspace: ebuf | ecoarse->xb alias | hb1 | hb2 | ints | Bp
    char* ws = (char*)d_ws;
    int2*  ebuf    = (int2*)ws;                ws += (size_t)NE * 8;            // 10.24 MB
    int2*  ecoarse = (int2*)ws;                                                // aliases xb
    unsigned short* xb  = (unsigned short*)ws; ws += (size_t)NN * DD * 2;       // 12.8 MB (>= ecoarse 10.24)
    unsigned short* hb1 = (unsigned short*)ws; ws += (size_t)NN * DD * 2;       // 12.8 MB
    unsigned short* hb2 = (unsigned short*)ws; ws += (size_t)NN * DD * 2;       // 12.8 MB
    int*   rowptr = (int*)ws;                  ws += (size_t)(NPAD + 16) * 4;
    int*   rangeCnt  = (int*)ws;               ws += (size_t)512 * 4;
    int*   rangeBase = (int*)ws;               ws += (size_t)512 * 4;
    int*   gcur      = (int*)ws;               ws += (size_t)512 * 4;
    unsigned short* Bp = (unsigned short*)ws;  // 3 * 16 KB

    const int* src = ei;
    const int* dst = ei + NE;

    // ---- CSR build: range hist -> scan -> bin -> place ----
    hipMemsetAsync(rangeCnt, 0, NRANGE * 4, stream);
    bpack_kernel<<<3, 256, 0, stream>>>(Wrel1, Wroot1, Wrel2, Wroot2, Wrel3, Wroot3, Bp);
    hist392_kernel<<<1250, 256, 0, stream>>>(dst, rangeCnt);
    scan392_kernel<<<1, 512, 0, stream>>>(rangeCnt, rangeBase, gcur, rowptr);
    p1_bin_kernel<<<1250, 512, 0, stream>>>(src, dst, w, gcur, ecoarse);
    p2_place_kernel<<<NRANGE, 512, 0, stream>>>(ecoarse, rangeBase, rowptr, ebuf);

    // ---- xb = bf16(x) (ecoarse dead now) ----
    f32_to_bf16_kernel<<<6250, 256, 0, stream>>>(x, xb);

    // ---- 3 fused layers (ping-pong xb -> hb1 -> hb2 -> out) ----
    fused_layer_kernel<true, false><<<NN / 16, 512, 0, stream>>>(
        xb, rowptr, ebuf, Bp, brel1, hb1);
    fused_layer_kernel<true, false><<<NN / 16, 512, 0, stream>>>(
        hb1, rowptr, ebuf, Bp + (size_t)4 * 256 * 8, brel2, hb2);
    fused_layer_kernel<false, true><<<NN / 16, 512, 0, stream>>>(
        hb2, rowptr, ebuf, Bp + (size_t)8 * 256 * 8, brel3, out);
}

// Round 10
// 265.233 us; speedup vs baseline: 1.6818x; 1.0905x over previous
//
#include <hip/hip_runtime.h>
#include <hip/hip_bf16.h>

#define NN 100000
#define NE 1280000
#define DD 64
#define RSHIFT 8             // 256-node dst ranges
#define NRANGE 392           // ceil(NN/256) = 391, pad to 392
#define NPAD (NRANGE * 256)  // 100352
#define RCAP 4096            // fixed edge-slot capacity per range (mean 3277, >14 sigma)
#define RPSTRIDE 257         // rowp stride per range (256 cursors + end sentinel)

typedef __attribute__((ext_vector_type(8))) short bf16x8;
typedef __attribute__((ext_vector_type(4))) float f32x4;

static __device__ __forceinline__ unsigned short f2bf(float f) {
    __hip_bfloat16 h = __float2bfloat16(f);
    return *reinterpret_cast<unsigned short*>(&h);
}

// ---------------------------------------------------------------------------
// x (fp32) -> bf16 copy. Grid 6250 x 256, 4 elems/thread (exact: 6.4M).
// ---------------------------------------------------------------------------
__global__ __launch_bounds__(256) void f32_to_bf16_kernel(
    const float* __restrict__ in, unsigned short* __restrict__ out)
{
    int i = (blockIdx.x * 256 + threadIdx.x) * 4;
    float4 v = *(const float4*)(in + i);
    ushort4 o;
    o.x = f2bf(v.x); o.y = f2bf(v.y); o.z = f2bf(v.z); o.w = f2bf(v.w);
    *(ushort4*)(out + i) = o;
}

// ---------------------------------------------------------------------------
// B-fragment pre-pack (blocks 0-2) + gcur fixed-base init (block 3). Grid 4.
// ---------------------------------------------------------------------------
__global__ __launch_bounds__(256) void bpack_kernel(
    const float* __restrict__ Wrel1, const float* __restrict__ Wroot1,
    const float* __restrict__ Wrel2, const float* __restrict__ Wroot2,
    const float* __restrict__ Wrel3, const float* __restrict__ Wroot3,
    unsigned short* __restrict__ Bp, int* __restrict__ gcur)
{
    int L = blockIdx.x;
    int tid = threadIdx.x;
    if (L == 3) {                         // gcur[r] = r*RCAP
        if (tid < NRANGE) gcur[tid] = tid * RCAP;
        if (tid + 256 < NRANGE) gcur[tid + 256] = (tid + 256) * RCAP;
        return;
    }
    const float* Wrel  = (L == 0) ? Wrel1  : (L == 1) ? Wrel2  : Wrel3;
    const float* Wroot = (L == 0) ? Wroot1 : (L == 1) ? Wroot2 : Wroot3;
    int wv = tid >> 6, lane = tid & 63, quad = lane >> 4, m16 = lane & 15;
    int n = wv * 16 + m16;
    unsigned short* o = Bp + (size_t)L * 4 * 256 * 8;
#pragma unroll
    for (int t = 0; t < 4; ++t)
#pragma unroll
        for (int j = 0; j < 8; ++j) {
            int k = t * 32 + quad * 8 + j;
            float wval = (k < 64) ? Wrel[k * 64 + n] : Wroot[(k - 64) * 64 + n];
            o[((size_t)t * 256 + tid) * 8 + j] = f2bf(wval);
        }
}

// ---------------------------------------------------------------------------
// P1: bin edges by 256-node dst range into FIXED-CAPACITY segments (no hist,
// no scan). 512 thr, 2 edges/thr, wave-shfl scan over 392 block-local bins.
// Record: src(17b)|local-dst(8b@17).
// ---------------------------------------------------------------------------
__global__ __launch_bounds__(512) void p1_bin_kernel(
    const int* __restrict__ src, const int* __restrict__ dst,
    const float* __restrict__ w, int* __restrict__ gcur,
    int2* __restrict__ ecoarse)
{
    __shared__ int2 stage[1024];
    __shared__ unsigned short sbkt[1024];
    __shared__ int cnt[NRANGE], ofs[NRANGE], gpos[NRANGE];
    __shared__ int wsum[8];

    int tid = threadIdx.x;
    int e0 = blockIdx.x * 1024 + tid * 2;
    int2   s2 = *(const int2*)(src + e0);
    int2   d2 = *(const int2*)(dst + e0);
    float2 w2 = *(const float2*)(w + e0);

    if (tid < NRANGE) cnt[tid] = 0;
    __syncthreads();

    int ss[2] = {s2.x, s2.y};
    int dd[2] = {d2.x, d2.y};
    float ww[2] = {w2.x, w2.y};
    int b[2], p[2];
#pragma unroll
    for (int i = 0; i < 2; ++i) {
        b[i] = dd[i] >> RSHIFT;
        p[i] = atomicAdd(&cnt[b[i]], 1);
    }
    __syncthreads();

    int sum = 0, v = 0;
    if (tid < NRANGE) {
        v = cnt[tid];
        int lane6 = tid & 63;
        sum = v;
#pragma unroll
        for (int o = 1; o < 64; o <<= 1) {
            int t = __shfl_up(sum, o);
            if (lane6 >= o) sum += t;
        }
        if (lane6 == 63 || tid == NRANGE - 1) wsum[tid >> 6] = sum;
        ofs[tid] = sum - v;
    }
    __syncthreads();
    if (tid < NRANGE) {
        int wid = tid >> 6;
        int pre = 0;
#pragma unroll
        for (int k = 0; k < 6; ++k) pre += (k < wid) ? wsum[k] : 0;
        ofs[tid] += pre;
        if (v > 0) gpos[tid] = atomicAdd(&gcur[tid], v);
    }
    __syncthreads();

#pragma unroll
    for (int i = 0; i < 2; ++i) {
        int slot = ofs[b[i]] + p[i];
        stage[slot] = make_int2(ss[i] | ((dd[i] & 255) << 17), __float_as_int(ww[i]));
        sbkt[slot] = (unsigned short)b[i];
    }
    __syncthreads();

#pragma unroll
    for (int u = 0; u < 2; ++u) {
        int j = tid + u * 512;
        int bb = sbkt[j];
        ecoarse[gpos[bb] + (j - ofs[bb])] = stage[j];
    }
}

// ---------------------------------------------------------------------------
// P2: per-range count + wave-shfl scan -> rowp (stride-257, end sentinel) +
// cursors, then place. Grid NRANGE(392) x 512 thr. beg = r*RCAP (fixed),
// end = gcur[r] (from p1). Final ebuf record: { src*128 (byte offset), w }.
// ---------------------------------------------------------------------------
__global__ __launch_bounds__(512) void p2_place_kernel(
    const int2* __restrict__ ecoarse, const int* __restrict__ gcur,
    int* __restrict__ rowp, int2* __restrict__ ebuf)
{
    __shared__ int cnt[256];
    __shared__ int wsum[4];
    int r = blockIdx.x, tid = threadIdx.x;
    int beg = r * RCAP;
    int end = gcur[r];

    if (tid < 256) cnt[tid] = 0;
    __syncthreads();

    for (int j = beg + tid; j < end; j += 512) {
        int2 rec = ecoarse[j];
        atomicAdd(&cnt[(rec.x >> 17) & 255], 1);
    }
    __syncthreads();

    int v = 0, sum = 0;
    if (tid < 256) {
        v = cnt[tid]; sum = v;
        int lane6 = tid & 63;
#pragma unroll
        for (int o = 1; o < 64; o <<= 1) {
            int t = __shfl_up(sum, o);
            if (lane6 >= o) sum += t;
        }
        if (lane6 == 63) wsum[tid >> 6] = sum;
    }
    __syncthreads();
    if (tid < 256) {
        int wid = tid >> 6;
        int pre = 0;
#pragma unroll
        for (int k = 0; k < 3; ++k) pre += (k < wid) ? wsum[k] : 0;
        int ex = beg + pre + sum - v;       // exclusive cursor for local node tid
        rowp[r * RPSTRIDE + tid] = ex;
        cnt[tid] = ex;
    }
    if (tid == 0) rowp[r * RPSTRIDE + 256] = end;   // range end sentinel
    __syncthreads();

    for (int j = beg + tid; j < end; j += 512) {
        int2 rec = ecoarse[j];
        int dl = (rec.x >> 17) & 255;
        int pp = atomicAdd(&cnt[dl], 1);
        ebuf[pp] = make_int2((rec.x & 0x1FFFF) << 7, rec.y);   // src*128 bytes
    }
}

// ---------------------------------------------------------------------------
// FUSED layer: CSR gather + dual GEMM + bias (+ReLU). Block = 512 thr =
// 8 waves = 16 nodes, half-wave per node (32 lanes = 32 channel pairs).
// Per 32-edge chunk: 64 lanes cooperatively load the chunk's records and
// ds_write_b64 them to a per-wave LDS slab (pad slots get w=0 at stage
// time); each half-wave streams 16 slots via half-uniform ds_read_b64
// (broadcast, conflict-free) -- no bpermute, no per-slot masking. Row
// address = pre-scaled byte offset + ch*4. 16 row loads in flight/wave.
// rowp is stride-257 per range: idx = node + (node>>8). Staging + MFMA +
// epilogue identical to verified r9.
// ---------------------------------------------------------------------------
template <bool RELU, bool OUT32>
__global__ __launch_bounds__(512) void fused_layer_kernel(
    const unsigned short* __restrict__ hb,   // input node table (gather + root)
    const int* __restrict__ rowp,
    const int2* __restrict__ ebuf,
    const unsigned short* __restrict__ Bp,   // [4][256][8] bf16 (this layer)
    const float* __restrict__ brel,
    void* __restrict__ outp)
{
    __shared__ __align__(16) unsigned int AstW[4 * 256];   // 4 KB
    __shared__ __align__(16) int2 seW[8][64];              // 4 KB per-wave slabs

    int tid = threadIdx.x;
    int lane = tid & 63;
    int wv = tid >> 6;            // 0..7
    int half = lane >> 5;         // node parity within wave
    int ch = lane & 31;           // channel pair
    int base = blockIdx.x * 16;
    int node = base + wv * 2 + half;
    int rr = base >> 8;           // range id (uniform per block)

    const char* __restrict__ hbase = (const char*)hb;
    unsigned chB = (unsigned)ch * 4;

    // B fragments + bias preloaded (only used by waves 0-3)
    bf16x8 bfrag[4];
    float bias = 0.f;
    if (wv < 4) {
#pragma unroll
        for (int t2 = 0; t2 < 4; ++t2)
            bfrag[t2] = *(const bf16x8*)(Bp + ((size_t)t2 * 256 + tid) * 8);
        bias = brel[(wv << 4) | (lane & 15)];
    }

    // root row (own node) issued early
    unsigned rootp = *(const unsigned*)(hbase + (size_t)node * 128 + chB);

    int beg = rowp[node + rr];
    int end = rowp[node + rr + 1];
    int deg = end - beg;

    float aL[4] = {0.f, 0.f, 0.f, 0.f};
    float aH[4] = {0.f, 0.f, 0.f, 0.f};

    for (int c = 0; c < deg; c += 32) {
        int nsl = deg - c; if (nsl > 32) nsl = 32;
        // stage chunk records; pad slots get w=0 (one select per chunk)
        {
            int j = c + ch;
            bool ok = j < deg;
            int2 e = ebuf[beg + (ok ? j : (deg - 1))];
            if (!ok) e.y = 0;
            seW[wv][half * 32 + ch] = e;
        }
        for (int s0 = 0; s0 < nsl; s0 += 16) {
#pragma unroll
            for (int i = 0; i < 16; ++i) {
                int2 rec = seW[wv][half * 32 + s0 + i];   // broadcast ds_read_b64
                float w = __int_as_float(rec.y);
                unsigned v = *(const unsigned*)(hbase + ((unsigned)rec.x + chB));
                aL[i & 3] = fmaf(w, __uint_as_float(v << 16), aL[i & 3]);
                aH[i & 3] = fmaf(w, __uint_as_float(v & 0xFFFF0000u), aH[i & 3]);
            }
        }
    }
    float accL = (aL[0] + aL[1]) + (aL[2] + aL[3]);
    float accH = (aH[0] + aH[1]) + (aH[2] + aH[3]);

    // stage agg (k 0..63) and root (k 64..127) pairs in fragment order
    int m = wv * 2 + half;                     // row 0..15
    int t = ch >> 4, q = (ch >> 2) & 3, jj = ch & 3;
    unsigned pack = ((unsigned)f2bf(accH) << 16) | (unsigned)f2bf(accL);
    AstW[t * 256 + (q * 16 + m) * 4 + jj] = pack;
    AstW[(2 + t) * 256 + (q * 16 + m) * 4 + jj] = rootp;
    __syncthreads();

    if (wv < 4) {
        int quad = lane >> 4, m16 = lane & 15;
        int n = wv * 16 + m16;
        f32x4 cacc = {0.f, 0.f, 0.f, 0.f};
#pragma unroll
        for (int t2 = 0; t2 < 4; ++t2) {
            bf16x8 a = *(const bf16x8*)&AstW[t2 * 256 + lane * 4];
            cacc = __builtin_amdgcn_mfma_f32_16x16x32_bf16(a, bfrag[t2], cacc, 0, 0, 0);
        }
#pragma unroll
        for (int reg = 0; reg < 4; ++reg) {
            int row = quad * 4 + reg;
            size_t onode = (size_t)base + row;
            float v2 = cacc[reg] + bias;
            if (RELU) v2 = fmaxf(v2, 0.f);
            if (OUT32) ((float*)outp)[onode * DD + n] = v2;
            else       ((unsigned short*)outp)[onode * DD + n] = f2bf(v2);
        }
    }
}

extern "C" void kernel_launch(void* const* d_in, const int* in_sizes, int n_in,
                              void* d_out, int out_size, void* d_ws, size_t ws_size,
                              hipStream_t stream)
{
    const float* x     = (const float*)d_in[0];
    const int*   ei    = (const int*)d_in[1];
    const float* w     = (const float*)d_in[2];
    const float* Wrel1 = (const float*)d_in[4];
    const float* brel1 = (const float*)d_in[5];
    const float* Wroot1= (const float*)d_in[6];
    const float* Wrel2 = (const float*)d_in[7];
    const float* brel2 = (const float*)d_in[8];
    const float* Wroot2= (const float*)d_in[9];
    const float* Wrel3 = (const float*)d_in[10];
    const float* brel3 = (const float*)d_in[11];
    const float* Wroot3= (const float*)d_in[12];

    float* out = (float*)d_out;

    // workspace: ebuf | ecoarse->xb alias | hb1 | hb2 | rowp | gcur | Bp
    char* ws = (char*)d_ws;
    int2*  ebuf    = (int2*)ws;                ws += (size_t)NRANGE * RCAP * 8;  // 12.85 MB
    int2*  ecoarse = (int2*)ws;                                                 // aliases xb
    unsigned short* xb  = (unsigned short*)ws; ws += (size_t)NPAD * DD * 2;      // 12.85 MB (== ecoarse size)
    unsigned short* hb1 = (unsigned short*)ws; ws += (size_t)NPAD * DD * 2;
    unsigned short* hb2 = (unsigned short*)ws; ws += (size_t)NPAD * DD * 2;
    int*   rowp  = (int*)ws;                   ws += (size_t)(NRANGE * RPSTRIDE + 16) * 4;
    int*   gcur  = (int*)ws;                   ws += (size_t)512 * 4;
    unsigned short* Bp = (unsigned short*)ws;  // 3 * 16 KB

    const int* src = ei;
    const int* dst = ei + NE;

    // ---- build: gcur init (bpack blk 3) -> bin -> place (no hist/scan) ----
    bpack_kernel<<<4, 256, 0, stream>>>(Wrel1, Wroot1, Wrel2, Wroot2,
                                        Wrel3, Wroot3, Bp, gcur);
    p1_bin_kernel<<<1250, 512, 0, stream>>>(src, dst, w, gcur, ecoarse);
    p2_place_kernel<<<NRANGE, 512, 0, stream>>>(ecoarse, gcur, rowp, ebuf);

    // ---- xb = bf16(x) (ecoarse dead now) ----
    f32_to_bf16_kernel<<<6250, 256, 0, stream>>>(x, xb);

    // ---- 3 fused layers (ping-pong xb -> hb1 -> hb2 -> out) ----
    fused_layer_kernel<true, false><<<NN / 16, 512, 0, stream>>>(
        xb, rowp, ebuf, Bp, brel1, hb1);
    fused_layer_kernel<true, false><<<NN / 16, 512, 0, stream>>>(
        hb1, rowp, ebuf, Bp + (size_t)4 * 256 * 8, brel2, hb2);
    fused_layer_kernel<false, true><<<NN / 16, 512, 0, stream>>>(
        hb2, rowp, ebuf, Bp + (size_t)8 * 256 * 8, brel3, out);
}

// Round 11
// 249.702 us; speedup vs baseline: 1.7864x; 1.0622x over previous
//
#include <hip/hip_runtime.h>
#include <hip/hip_bf16.h>

#define NN 100000
#define NE 1280000
#define DD 64
#define RSHIFT 9             // 512-node dst ranges
#define NRANGE 196           // ceil(NN/512)
#define NPAD (NRANGE * 512)  // 100352
#define RCAP 8192            // fixed edge-slot capacity per range (mean 6531, 20 sigma)
#define RPSTRIDE 513         // rowp stride per range (512 cursors + end sentinel)

typedef __attribute__((ext_vector_type(8))) short bf16x8;
typedef __attribute__((ext_vector_type(4))) float f32x4;

static __device__ __forceinline__ unsigned short f2bf(float f) {
    __hip_bfloat16 h = __float2bfloat16(f);
    return *reinterpret_cast<unsigned short*>(&h);
}

// ---------------------------------------------------------------------------
// x (fp32) -> bf16 copy. Grid 6250 x 256, 4 elems/thread (exact: 6.4M).
// ---------------------------------------------------------------------------
__global__ __launch_bounds__(256) void f32_to_bf16_kernel(
    const float* __restrict__ in, unsigned short* __restrict__ out)
{
    int i = (blockIdx.x * 256 + threadIdx.x) * 4;
    float4 v = *(const float4*)(in + i);
    ushort4 o;
    o.x = f2bf(v.x); o.y = f2bf(v.y); o.z = f2bf(v.z); o.w = f2bf(v.w);
    *(ushort4*)(out + i) = o;
}

// ---------------------------------------------------------------------------
// B-fragment pre-pack (blocks 0-2) + gcur fixed-base init (block 3). Grid 4.
// ---------------------------------------------------------------------------
__global__ __launch_bounds__(256) void bpack_kernel(
    const float* __restrict__ Wrel1, const float* __restrict__ Wroot1,
    const float* __restrict__ Wrel2, const float* __restrict__ Wroot2,
    const float* __restrict__ Wrel3, const float* __restrict__ Wroot3,
    unsigned short* __restrict__ Bp, int* __restrict__ gcur)
{
    int L = blockIdx.x;
    int tid = threadIdx.x;
    if (L == 3) {                         // gcur[r] = r*RCAP
        if (tid < NRANGE) gcur[tid] = tid * RCAP;
        return;
    }
    const float* Wrel  = (L == 0) ? Wrel1  : (L == 1) ? Wrel2  : Wrel3;
    const float* Wroot = (L == 0) ? Wroot1 : (L == 1) ? Wroot2 : Wroot3;
    int wv = tid >> 6, lane = tid & 63, quad = lane >> 4, m16 = lane & 15;
    int n = wv * 16 + m16;
    unsigned short* o = Bp + (size_t)L * 4 * 256 * 8;
#pragma unroll
    for (int t = 0; t < 4; ++t)
#pragma unroll
        for (int j = 0; j < 8; ++j) {
            int k = t * 32 + quad * 8 + j;
            float wval = (k < 64) ? Wrel[k * 64 + n] : Wroot[(k - 64) * 64 + n];
            o[((size_t)t * 256 + tid) * 8 + j] = f2bf(wval);
        }
}

// ---------------------------------------------------------------------------
// P1: bin edges by 512-node dst range into FIXED-CAPACITY segments.
// 512 thr, 4 edges/thr (2048-edge chunks, grid 625), wave-shfl scan over
// 196 bins. Runs avg 10.4 recs (~83B) -> near-coalesced segment writes.
// Record: src(17b)|local-dst(9b@17).
// ---------------------------------------------------------------------------
__global__ __launch_bounds__(512) void p1_bin_kernel(
    const int* __restrict__ src, const int* __restrict__ dst,
    const float* __restrict__ w, int* __restrict__ gcur,
    int2* __restrict__ ecoarse)
{
    __shared__ int2 stage[2048];                 // 16 KB
    __shared__ unsigned char sbkt[2048];         // 2 KB
    __shared__ int cnt[NRANGE], ofs[NRANGE], gpos[NRANGE];
    __shared__ int wsum[4];

    int tid = threadIdx.x;
    int e0 = blockIdx.x * 2048 + tid * 4;
    int4   s4 = *(const int4*)(src + e0);
    int4   d4 = *(const int4*)(dst + e0);
    float4 w4 = *(const float4*)(w + e0);

    if (tid < NRANGE) cnt[tid] = 0;
    __syncthreads();

    int ss[4] = {s4.x, s4.y, s4.z, s4.w};
    int dd[4] = {d4.x, d4.y, d4.z, d4.w};
    float ww[4] = {w4.x, w4.y, w4.z, w4.w};
    int b[4], p[4];
#pragma unroll
    for (int i = 0; i < 4; ++i) {
        b[i] = dd[i] >> RSHIFT;
        p[i] = atomicAdd(&cnt[b[i]], 1);
    }
    __syncthreads();

    int sum = 0, v = 0;
    if (tid < NRANGE) {
        v = cnt[tid];
        int lane6 = tid & 63;
        sum = v;
#pragma unroll
        for (int o = 1; o < 64; o <<= 1) {
            int t = __shfl_up(sum, o);
            if (lane6 >= o) sum += t;
        }
        if (lane6 == 63 || tid == NRANGE - 1) wsum[tid >> 6] = sum;
        ofs[tid] = sum - v;
    }
    __syncthreads();
    if (tid < NRANGE) {
        int wid = tid >> 6;
        int pre = 0;
#pragma unroll
        for (int k = 0; k < 3; ++k) pre += (k < wid) ? wsum[k] : 0;
        ofs[tid] += pre;
        if (v > 0) gpos[tid] = atomicAdd(&gcur[tid], v);
    }
    __syncthreads();

#pragma unroll
    for (int i = 0; i < 4; ++i) {
        int slot = ofs[b[i]] + p[i];
        stage[slot] = make_int2(ss[i] | ((dd[i] & 511) << 17), __float_as_int(ww[i]));
        sbkt[slot] = (unsigned char)b[i];
    }
    __syncthreads();

#pragma unroll
    for (int u = 0; u < 4; ++u) {
        int j = tid + u * 512;
        int bb = sbkt[j];
        ecoarse[gpos[bb] + (j - ofs[bb])] = stage[j];
    }
}

// ---------------------------------------------------------------------------
// P2: per-range count + wave-shfl scan -> rowp (stride-513, end sentinel) +
// cursors, then place. Grid NRANGE(196) x 1024 thr. beg = r*RCAP (fixed),
// end = gcur[r] (from p1). Final ebuf record: { src*128 (byte offset), w }.
// ---------------------------------------------------------------------------
__global__ __launch_bounds__(1024) void p2_place_kernel(
    const int2* __restrict__ ecoarse, const int* __restrict__ gcur,
    int* __restrict__ rowp, int2* __restrict__ ebuf)
{
    __shared__ int cnt[512];
    __shared__ int wsum[8];
    int r = blockIdx.x, tid = threadIdx.x;
    int beg = r * RCAP;
    int end = gcur[r];

    if (tid < 512) cnt[tid] = 0;
    __syncthreads();

    for (int j = beg + tid; j < end; j += 1024) {
        int2 rec = ecoarse[j];
        atomicAdd(&cnt[(rec.x >> 17) & 511], 1);
    }
    __syncthreads();

    int v = 0, sum = 0;
    if (tid < 512) {
        v = cnt[tid]; sum = v;
        int lane6 = tid & 63;
#pragma unroll
        for (int o = 1; o < 64; o <<= 1) {
            int t = __shfl_up(sum, o);
            if (lane6 >= o) sum += t;
        }
        if (lane6 == 63) wsum[tid >> 6] = sum;
    }
    __syncthreads();
    if (tid < 512) {
        int wid = tid >> 6;
        int pre = 0;
#pragma unroll
        for (int k = 0; k < 7; ++k) pre += (k < wid) ? wsum[k] : 0;
        int ex = beg + pre + sum - v;       // exclusive cursor for local node tid
        rowp[r * RPSTRIDE + tid] = ex;
        cnt[tid] = ex;
    }
    if (tid == 0) rowp[r * RPSTRIDE + 512] = end;   // range end sentinel
    __syncthreads();

    for (int j = beg + tid; j < end; j += 1024) {
        int2 rec = ecoarse[j];
        int dl = (rec.x >> 17) & 511;
        int pp = atomicAdd(&cnt[dl], 1);
        ebuf[pp] = make_int2((rec.x & 0x1FFFF) << 7, rec.y);   // src*128 bytes
    }
}

// ---------------------------------------------------------------------------
// FUSED layer: CSR gather + dual GEMM + bias (+ReLU). Block = 512 thr =
// 8 waves = 16 nodes, half-wave per node (32 lanes = 32 channel pairs).
// Per 32-edge chunk: 64 lanes cooperatively load the chunk's records and
// ds_write_b64 them to a per-wave LDS slab (pad slots get w=0 at stage
// time); each half-wave streams 16 slots via half-uniform ds_read_b64
// (broadcast, conflict-free) -- no bpermute, no per-slot masking. Row
// address = pre-scaled byte offset + ch*4. 16 row loads in flight/wave.
// rowp is stride-513 per range: idx = node + (node>>9). Staging + MFMA +
// epilogue identical to verified r10.
// ---------------------------------------------------------------------------
template <bool RELU, bool OUT32>
__global__ __launch_bounds__(512) void fused_layer_kernel(
    const unsigned short* __restrict__ hb,   // input node table (gather + root)
    const int* __restrict__ rowp,
    const int2* __restrict__ ebuf,
    const unsigned short* __restrict__ Bp,   // [4][256][8] bf16 (this layer)
    const float* __restrict__ brel,
    void* __restrict__ outp)
{
    __shared__ __align__(16) unsigned int AstW[4 * 256];   // 4 KB
    __shared__ __align__(16) int2 seW[8][64];              // 4 KB per-wave slabs

    int tid = threadIdx.x;
    int lane = tid & 63;
    int wv = tid >> 6;            // 0..7
    int half = lane >> 5;         // node parity within wave
    int ch = lane & 31;           // channel pair
    int base = blockIdx.x * 16;
    int node = base + wv * 2 + half;
    int rr = base >> 9;           // range id (uniform per block)

    const char* __restrict__ hbase = (const char*)hb;
    unsigned chB = (unsigned)ch * 4;

    // B fragments + bias preloaded (only used by waves 0-3)
    bf16x8 bfrag[4];
    float bias = 0.f;
    if (wv < 4) {
#pragma unroll
        for (int t2 = 0; t2 < 4; ++t2)
            bfrag[t2] = *(const bf16x8*)(Bp + ((size_t)t2 * 256 + tid) * 8);
        bias = brel[(wv << 4) | (lane & 15)];
    }

    // root row (own node) issued early
    unsigned rootp = *(const unsigned*)(hbase + (size_t)node * 128 + chB);

    int beg = rowp[node + rr];
    int end = rowp[node + rr + 1];
    int deg = end - beg;

    float aL[4] = {0.f, 0.f, 0.f, 0.f};
    float aH[4] = {0.f, 0.f, 0.f, 0.f};

    for (int c = 0; c < deg; c += 32) {
        int nsl = deg - c; if (nsl > 32) nsl = 32;
        // stage chunk records; pad slots get w=0 (one select per chunk)
        {
            int j = c + ch;
            bool ok = j < deg;
            int2 e = ebuf[beg + (ok ? j : (deg - 1))];
            if (!ok) e.y = 0;
            seW[wv][half * 32 + ch] = e;
        }
        for (int s0 = 0; s0 < nsl; s0 += 16) {
#pragma unroll
            for (int i = 0; i < 16; ++i) {
                int2 rec = seW[wv][half * 32 + s0 + i];   // broadcast ds_read_b64
                float w = __int_as_float(rec.y);
                unsigned v = *(const unsigned*)(hbase + ((unsigned)rec.x + chB));
                aL[i & 3] = fmaf(w, __uint_as_float(v << 16), aL[i & 3]);
                aH[i & 3] = fmaf(w, __uint_as_float(v & 0xFFFF0000u), aH[i & 3]);
            }
        }
    }
    float accL = (aL[0] + aL[1]) + (aL[2] + aL[3]);
    float accH = (aH[0] + aH[1]) + (aH[2] + aH[3]);

    // stage agg (k 0..63) and root (k 64..127) pairs in fragment order
    int m = wv * 2 + half;                     // row 0..15
    int t = ch >> 4, q = (ch >> 2) & 3, jj = ch & 3;
    unsigned pack = ((unsigned)f2bf(accH) << 16) | (unsigned)f2bf(accL);
    AstW[t * 256 + (q * 16 + m) * 4 + jj] = pack;
    AstW[(2 + t) * 256 + (q * 16 + m) * 4 + jj] = rootp;
    __syncthreads();

    if (wv < 4) {
        int quad = lane >> 4, m16 = lane & 15;
        int n = wv * 16 + m16;
        f32x4 cacc = {0.f, 0.f, 0.f, 0.f};
#pragma unroll
        for (int t2 = 0; t2 < 4; ++t2) {
            bf16x8 a = *(const bf16x8*)&AstW[t2 * 256 + lane * 4];
            cacc = __builtin_amdgcn_mfma_f32_16x16x32_bf16(a, bfrag[t2], cacc, 0, 0, 0);
        }
#pragma unroll
        for (int reg = 0; reg < 4; ++reg) {
            int row = quad * 4 + reg;
            size_t onode = (size_t)base + row;
            float v2 = cacc[reg] + bias;
            if (RELU) v2 = fmaxf(v2, 0.f);
            if (OUT32) ((float*)outp)[onode * DD + n] = v2;
            else       ((unsigned short*)outp)[onode * DD + n] = f2bf(v2);
        }
    }
}

extern "C" void kernel_launch(void* const* d_in, const int* in_sizes, int n_in,
                              void* d_out, int out_size, void* d_ws, size_t ws_size,
                              hipStream_t stream)
{
    const float* x     = (const float*)d_in[0];
    const int*   ei    = (const int*)d_in[1];
    const float* w     = (const float*)d_in[2];
    const float* Wrel1 = (const float*)d_in[4];
    const float* brel1 = (const float*)d_in[5];
    const float* Wroot1= (const float*)d_in[6];
    const float* Wrel2 = (const float*)d_in[7];
    const float* brel2 = (const float*)d_in[8];
    const float* Wroot2= (const float*)d_in[9];
    const float* Wrel3 = (const float*)d_in[10];
    const float* brel3 = (const float*)d_in[11];
    const float* Wroot3= (const float*)d_in[12];

    float* out = (float*)d_out;

    // workspace: ebuf | ecoarse->xb alias | hb1 | hb2 | rowp | gcur | Bp
    char* ws = (char*)d_ws;
    int2*  ebuf    = (int2*)ws;                ws += (size_t)NRANGE * RCAP * 8;  // 12.85 MB
    int2*  ecoarse = (int2*)ws;                                                 // aliases xb
    unsigned short* xb  = (unsigned short*)ws; ws += (size_t)NRANGE * RCAP * 8;  // 12.85 MB (>= xb 12.85)
    unsigned short* hb1 = (unsigned short*)ws; ws += (size_t)NPAD * DD * 2;
    unsigned short* hb2 = (unsigned short*)ws; ws += (size_t)NPAD * DD * 2;
    int*   rowp  = (int*)ws;                   ws += (size_t)(NRANGE * RPSTRIDE + 16) * 4;
    int*   gcur  = (int*)ws;                   ws += (size_t)256 * 4;
    unsigned short* Bp = (unsigned short*)ws;  // 3 * 16 KB

    const int* src = ei;
    const int* dst = ei + NE;

    // ---- build: gcur init (bpack blk 3) -> bin -> place (no hist/scan) ----
    bpack_kernel<<<4, 256, 0, stream>>>(Wrel1, Wroot1, Wrel2, Wroot2,
                                        Wrel3, Wroot3, Bp, gcur);
    p1_bin_kernel<<<625, 512, 0, stream>>>(src, dst, w, gcur, ecoarse);
    p2_place_kernel<<<NRANGE, 1024, 0, stream>>>(ecoarse, gcur, rowp, ebuf);

    // ---- xb = bf16(x) (ecoarse dead now) ----
    f32_to_bf16_kernel<<<6250, 256, 0, stream>>>(x, xb);

    // ---- 3 fused layers (ping-pong xb -> hb1 -> hb2 -> out) ----
    fused_layer_kernel<true, false><<<NN / 16, 512, 0, stream>>>(
        xb, rowp, ebuf, Bp, brel1, hb1);
    fused_layer_kernel<true, false><<<NN / 16, 512, 0, stream>>>(
        hb1, rowp, ebuf, Bp + (size_t)4 * 256 * 8, brel2, hb2);
    fused_layer_kernel<false, true><<<NN / 16, 512, 0, stream>>>(
        hb2, rowp, ebuf, Bp + (size_t)8 * 256 * 8, brel3, out);
}